// Round 12
// baseline (126.450 us; speedup 1.0000x reference)
//
#include <hip/hip_runtime.h>

constexpr int CN   = 32;
constexpr int CIN  = 64;
constexpr int CH   = 128;
constexpr int CW   = 128;
constexpr int COUT = 128;
constexpr int OHh  = 126;
constexpr int OWw  = 126;
constexpr int KTOT = 576;

typedef __attribute__((ext_vector_type(8))) short bf16x8;
typedef __attribute__((ext_vector_type(4))) float f32x4;

__device__ __forceinline__ unsigned short f2bf(float f) {
  union { float f; unsigned u; } v; v.f = f;
  unsigned u = v.u;
  u += 0x7FFFu + ((u >> 16) & 1u);   // RNE
  return (unsigned short)(u >> 16);
}

__device__ __forceinline__ void gload_lds16(const unsigned short* g, unsigned short* l) {
  __builtin_amdgcn_global_load_lds(
      (const __attribute__((address_space(1))) unsigned int*)g,
      (__attribute__((address_space(3))) unsigned int*)l, 16, 0, 0);
}

// ---- prep: x (N,Ci,H,W) fp32 -> xt[n][h][c][ci64] bf16, T2 swizzle baked ------------
// Within each 32-ci half, logical octet o stored at slot o ^ ((c>>1)&3).
__global__ __launch_bounds__(256) void prep_xt_kernel(const float* __restrict__ x,
                                                      unsigned short* __restrict__ xt) {
  __shared__ __align__(16) unsigned short s[128][72];
  const int b = blockIdx.x;            // n*128 + h
  const int n = b >> 7, h = b & 127;
  const float* src = x + (size_t)n * CIN * CH * CW + (size_t)h * CW;
  const int t = threadIdx.x;
  #pragma unroll
  for (int r = 0; r < 8; ++r) {
    int idx = r * 256 + t;
    int ci = idx >> 5, c0 = (idx & 31) << 2;
    float4 v = *(const float4*)(src + (size_t)ci * (CH * CW) + c0);
    s[c0 + 0][ci] = f2bf(v.x);
    s[c0 + 1][ci] = f2bf(v.y);
    s[c0 + 2][ci] = f2bf(v.z);
    s[c0 + 3][ci] = f2bf(v.w);
  }
  __syncthreads();
  unsigned short* dst = xt + (size_t)b * 8192;
  #pragma unroll
  for (int r = 0; r < 4; ++r) {
    int idx = r * 256 + t;
    int c = idx >> 3, sl = idx & 7;
    int half = sl >> 2, q = sl & 3;
    int lo = q ^ ((c >> 1) & 3);
    uint4 v = *(const uint4*)&s[c][half * 32 + lo * 8];
    *(uint4*)(dst + (size_t)c * 64 + sl * 8) = v;
  }
}

// ---- prep: W -> wt4, A-fragment-ordered: [p:18][mi:8][lane:64][j:8] -----------------
// p = G*3+kw, G = kh*2+half; co = mi*16+(lane&15); ci = half*32+(lane>>4)*8+j.
__global__ void prep_wt4_kernel(const float* __restrict__ w,
                                unsigned short* __restrict__ wt4) {
  int e = blockIdx.x * 256 + threadIdx.x;
  if (e >= COUT * KTOT) return;
  int j = e & 7, lane = (e >> 3) & 63, mi = (e >> 9) & 7;
  int p = e >> 12;                 // 0..17
  int G = p / 3, kw = p - G * 3;
  int kh = G >> 1, half = G & 1;
  int co = mi * 16 + (lane & 15);
  int ci = half * 32 + (lane >> 4) * 8 + j;
  wt4[e] = f2bf(w[co * 576 + ci * 9 + kh * 3 + kw]);
}

// ---- main: 256 thr, 4 waves, wave = 128co x 32px, tile 128 x 128px (1 row) ----------
// gload_lds staging from xt (2/wave/group), bfr double-buffer prefetch, af streamed
// from L1-shared wt4 (all 4 waves read identical lines), 1 barrier/group, 4 blk/CU.
__global__ __launch_bounds__(256, 4)
void conv_min_mfma12(const unsigned short* __restrict__ xt,
                     const unsigned short* __restrict__ wt4,
                     const float* __restrict__ bias,
                     float* __restrict__ out) {
  __shared__ __align__(16) unsigned short sX[2][132][32];   // 16896 B total, 8448 B/buf

  const int t   = threadIdx.x;
  const int bid = blockIdx.x;
  const int swz = (bid & 7) * 504 + (bid >> 3);   // 4032 = 8*504, bijective
  const int n   = swz / OHh;
  const int oh  = swz - n * OHh;                  // 0..125

  const int lane = t & 63, w = t >> 6;            // w = pixel quarter 0..3
  const int lg = lane >> 4, ln = lane & 15;

  // staging: wave w handles segments 2w, 2w+1 (16 c-columns each)
  const int seg0 = w * 2;
  const int cA = seg0 * 16 + (lane >> 2);
  const int srcA = cA * 64 + (lane & 3) * 8;      // + h*8192 + half*32
  const int srcB = srcA + 16 * 64;

  // B fragment byte-offsets (chunk swizzle ni-invariant under +16 rows)
  int Bb[3];
  #pragma unroll
  for (int kw = 0; kw < 3; ++kw) {
    int row = w * 32 + ln + kw;                   // +ni*16 <=129 (pad rows zeroed)
    int ch = lg ^ ((row >> 1) & 3);
    Bb[kw] = row * 64 + ch * 16;                  // + buf*8448 + ni*1024
  }
  const unsigned short* wlane = wt4 + lane * 8;   // + (p*8+mi)*512

  f32x4 acc[8][2];
  #pragma unroll
  for (int i = 0; i < 8; ++i)
    #pragma unroll
    for (int j = 0; j < 2; ++j)
      acc[i][j] = (f32x4){0.f, 0.f, 0.f, 0.f};

  bf16x8 bfr[2][2];

  auto stage = [&](int G, int buf) {
    const int h = oh + (G >> 1);                  // <=127
    const size_t base = (size_t)(n * 128 + h) * 8192 + (G & 1) * 32;
    unsigned short* dst = &sX[buf][0][0] + seg0 * 512;
    gload_lds16(xt + base + srcA, dst);
    gload_lds16(xt + base + srcB, dst + 512);
  };
  auto ldB = [&](int p, int slot) {
    const int G = p / 3, kw = p - G * 3, buf = G & 1;
    #pragma unroll
    for (int ni = 0; ni < 2; ++ni)
      bfr[slot][ni] = *(const bf16x8*)((const char*)&sX[0][0][0] +
                                       buf * 8448 + Bb[kw] + ni * 1024);
  };

  // prologue: zero pad rows (128..131 of both buffers), stage group 0
  if (t < 128) {
    int buf = t >> 6, i = t & 63;
    ((unsigned*)&sX[buf][128][0])[i] = 0u;
  }
  stage(0, 0);
  asm volatile("s_waitcnt vmcnt(0) lgkmcnt(0)" ::: "memory");
  __builtin_amdgcn_s_barrier();
  __builtin_amdgcn_sched_barrier(0);
  ldB(0, 0);

  #pragma unroll
  for (int p = 0; p < 18; ++p) {
    const int G = p / 3, kw = p - G * 3, cur = p & 1;
    if (kw == 0 && G < 5) stage(G + 1, (G & 1) ^ 1);
    if (kw < 2) ldB(p + 1, cur ^ 1);              // prefetch next phase (same buffer)
    __builtin_amdgcn_s_setprio(1);
    #pragma unroll
    for (int mi = 0; mi < 8; ++mi) {              // af streamed (L1-shared wt4)
      bf16x8 af = *(const bf16x8*)(wlane + (p * 8 + mi) * 512);
      #pragma unroll
      for (int ni = 0; ni < 2; ++ni)
        acc[mi][ni] = __builtin_amdgcn_mfma_f32_16x16x32_bf16(
            af, bfr[cur][ni], acc[mi][ni], 0, 0, 0);
    }
    __builtin_amdgcn_s_setprio(0);
    if (kw == 2 && G < 5) {
      asm volatile("s_waitcnt vmcnt(0)" ::: "memory");  // stage(G+1) landed (~3 phases old)
      __builtin_amdgcn_s_barrier();                     // all waves: next buf ready
      __builtin_amdgcn_sched_barrier(0);
      ldB(p + 1, cur ^ 1);                              // first prefetch from new buffer
    }
  }

  // epilogue: (acc + bias)*0.5, min over all 128 co (in-thread mi,r + lane groups)
  // C/D: col = ln (px within ni-frag), row = lg*4 + r -> co = mi*16 + lg*4 + r
  #pragma unroll
  for (int ni = 0; ni < 2; ++ni) {
    float m = 3.4e38f;
    #pragma unroll
    for (int mi = 0; mi < 8; ++mi)
      #pragma unroll
      for (int r = 0; r < 4; ++r)
        m = fminf(m, (acc[mi][ni][r] + bias[mi * 16 + lg * 4 + r]) * 0.5f);
    m = fminf(m, __shfl_xor(m, 16));
    m = fminf(m, __shfl_xor(m, 32));
    int col = w * 32 + ni * 16 + ln;
    if (lg == 0 && col < OWw)
      out[((size_t)n * OHh + oh) * OWw + col] = m;
  }
}

// ================= fallback (direct-compute path, used only if ws unusable) =========
__global__ __launch_bounds__(256, 2)
void conv_min_fb(const float* __restrict__ x, const float* __restrict__ w,
                 const float* __restrict__ bias, float* __restrict__ out) {
  __shared__ __align__(16) unsigned short sW[128][40];
  __shared__ __align__(16) unsigned short sX[128][40];
  __shared__ float sBias[COUT];
  __shared__ float sRed[2][128];
  const int t = threadIdx.x, bid = blockIdx.x;
  const int n = bid / OHh, oh = bid - n * OHh;
  if (t < COUT) sBias[t] = bias[t];
  const int hq = t & 7, q = t >> 3, c0 = q * 4;
  const int wco = t >> 1, whalf = t & 1;
  const int lane = t & 63, lg = lane >> 4, ln = lane & 15;
  const int wv = t >> 6, wc = wv & 1, wp = wv >> 1;
  f32x4 acc[4][4];
  #pragma unroll
  for (int i = 0; i < 4; ++i)
    #pragma unroll
    for (int j = 0; j < 4; ++j) acc[i][j] = (f32x4){0.f, 0.f, 0.f, 0.f};
  const float* xn = x + (size_t)n * CIN * CH * CW;
  for (int s = 0; s < 18; ++s) {
    const int kw_s = s / 6;
    const int rembase = (s - kw_s * 6) * 32;
    float4 xa[2], xb[2]; int kkp[2];
    #pragma unroll
    for (int pi = 0; pi < 2; ++pi) {
      const int kk = 2 * hq + 16 * pi; kkp[pi] = kk;
      int rem0 = rembase + kk, ci0 = rem0 / 3, kh0 = rem0 - ci0 * 3;
      int rem1 = rem0 + 1, ci1 = rem1 / 3, kh1 = rem1 - ci1 * 3;
      xa[pi] = *(const float4*)(xn + (ci0 * CH + (oh + kh0)) * CW + c0);
      xb[pi] = *(const float4*)(xn + (ci1 * CH + (oh + kh1)) * CW + c0);
    }
    unsigned tmp[8];
    #pragma unroll
    for (int e = 0; e < 8; ++e) {
      int kk = whalf * 16 + 2 * e;
      int rem0 = rembase + kk, ci0 = rem0 / 3, kh0 = rem0 - ci0 * 3;
      int rem1 = rem0 + 1, ci1 = rem1 / 3, kh1 = rem1 - ci1 * 3;
      tmp[e] = (unsigned)f2bf(w[wco * 576 + ci0 * 9 + kh0 * 3 + kw_s]) |
               ((unsigned)f2bf(w[wco * 576 + ci1 * 9 + kh1 * 3 + kw_s]) << 16);
    }
    __syncthreads();
    #pragma unroll
    for (int pi = 0; pi < 2; ++pi)
      #pragma unroll
      for (int j = 0; j < 4; ++j) {
        int p = c0 + j - kw_s;
        unsigned pk = (unsigned)f2bf(((const float*)&xa[pi])[j]) |
                      ((unsigned)f2bf(((const float*)&xb[pi])[j]) << 16);
        if (p >= 0) *(unsigned*)&sX[p][kkp[pi]] = pk;
      }
    *(uint4*)&sW[wco][whalf * 16] = make_uint4(tmp[0], tmp[1], tmp[2], tmp[3]);
    *(uint4*)&sW[wco][whalf * 16 + 8] = make_uint4(tmp[4], tmp[5], tmp[6], tmp[7]);
    __syncthreads();
    bf16x8 af[4], bfr[4];
    #pragma unroll
    for (int mi = 0; mi < 4; ++mi) af[mi] = *(const bf16x8*)&sW[wc * 64 + mi * 16 + ln][lg * 8];
    #pragma unroll
    for (int ni = 0; ni < 4; ++ni) bfr[ni] = *(const bf16x8*)&sX[wp * 64 + ni * 16 + ln][lg * 8];
    #pragma unroll
    for (int mi = 0; mi < 4; ++mi)
      #pragma unroll
      for (int ni = 0; ni < 4; ++ni)
        acc[mi][ni] = __builtin_amdgcn_mfma_f32_16x16x32_bf16(af[mi], bfr[ni], acc[mi][ni], 0, 0, 0);
  }
  #pragma unroll
  for (int ni = 0; ni < 4; ++ni) {
    float m = 3.4e38f;
    #pragma unroll
    for (int mi = 0; mi < 4; ++mi)
      #pragma unroll
      for (int r = 0; r < 4; ++r)
        m = fminf(m, (acc[mi][ni][r] + sBias[wc * 64 + mi * 16 + lg * 4 + r]) * 0.5f);
    m = fminf(m, __shfl_xor(m, 16));
    m = fminf(m, __shfl_xor(m, 32));
    if (lg == 0) sRed[wc][wp * 64 + ni * 16 + ln] = m;
  }
  __syncthreads();
  if (t < OWw) out[(size_t)(n * OHh + oh) * OWw + t] = fminf(sRed[0][t], sRed[1][t]);
}

extern "C" void kernel_launch(void* const* d_in, const int* in_sizes, int n_in,
                              void* d_out, int out_size, void* d_ws, size_t ws_size,
                              hipStream_t stream) {
  const float* x    = (const float*)d_in[0];
  const float* w    = (const float*)d_in[1];
  const float* bias = (const float*)d_in[2];
  float* out = (float*)d_out;

  const size_t XT_BYTES = (size_t)CN * CH * CW * CIN * 2;  // 67,108,864
  const size_t WT_BYTES = (size_t)COUT * KTOT * 2;         // 147,456

  if (d_ws && ws_size >= XT_BYTES + WT_BYTES) {
    unsigned short* xt  = (unsigned short*)d_ws;
    unsigned short* wt4 = (unsigned short*)((char*)d_ws + XT_BYTES);
    prep_xt_kernel<<<CN * CH, 256, 0, stream>>>(x, xt);
    prep_wt4_kernel<<<(COUT * KTOT + 255) / 256, 256, 0, stream>>>(w, wt4);
    conv_min_mfma12<<<CN * OHh, 256, 0, stream>>>(xt, wt4, bias, out);
  } else {
    conv_min_fb<<<CN * OHh, 256, 0, stream>>>(x, w, bias, out);
  }
}

// Round 13
// 118.328 us; speedup vs baseline: 1.0686x; 1.0686x over previous
//
#include <hip/hip_runtime.h>
#include <hip/hip_bf16.h>

constexpr int CN   = 32;
constexpr int CIN  = 64;
constexpr int CH   = 128;
constexpr int CW   = 128;
constexpr int COUT = 128;
constexpr int OHh  = 126;
constexpr int OWw  = 126;
constexpr int KTOT = 576;

typedef __attribute__((ext_vector_type(8))) short bf16x8;
typedef __attribute__((ext_vector_type(4))) float f32x4;

__device__ __forceinline__ unsigned short f2bf(float f) {
  union { float f; unsigned u; } v; v.f = f;
  unsigned u = v.u;
  u += 0x7FFFu + ((u >> 16) & 1u);   // RNE
  return (unsigned short)(u >> 16);
}

__device__ __forceinline__ unsigned packbf2(float a, float b) {
  union { __hip_bfloat162 h; unsigned u; } v;
  v.h = __float22bfloat162_rn(make_float2(a, b));   // v_cvt_pk_bf16_f32
  return v.u;
}

// ---- prep: W -> wt4, A-fragment-ordered: [p:18][mi:8][lane:64][j:8] -----------------
// p = G*3+kw, G = kh*2+half; co = mi*16+(lane&15); ci = half*32+(lane>>4)*8+j.
__global__ void prep_wt4_kernel(const float* __restrict__ w,
                                unsigned short* __restrict__ wt4) {
  int e = blockIdx.x * 256 + threadIdx.x;
  if (e >= COUT * KTOT) return;
  int j = e & 7, lane = (e >> 3) & 63, mi = (e >> 9) & 7;
  int p = e >> 12;                 // 0..17
  int G = p / 3, kw = p - G * 3;
  int kh = G >> 1, half = G & 1;
  int co = mi * 16 + (lane & 15);
  int ci = half * 32 + (lane >> 4) * 8 + j;
  wt4[e] = f2bf(w[co * 576 + ci * 9 + kh * 3 + kw]);
}

// ---- main: 256 thr, 4 waves; wave = 128co(8mi) x 64px(4ni); block = 128co x 256px ---
// B-LDS bytes /4 vs 4x4 tiles (the r12-diagnosed fragment-BW wall); af identical across
// waves, streamed from L1-hot wt4; direct-x reg-cvt staging (no prep_xt); 1 barrier/grp.
__global__ __launch_bounds__(256, 2)
void conv_min_mfma13(const float* __restrict__ x,
                     const unsigned short* __restrict__ wt4,
                     const float* __restrict__ bias,
                     float* __restrict__ out) {
  // [buf][row][c:132][ci-half:32]; bytes: row-subtile 8448, buffer 16896, total 33792
  __shared__ __align__(16) unsigned short sX[2][2][132][32];

  const int t   = threadIdx.x;
  const int bid = blockIdx.x;
  const int swz = (bid & 7) * 252 + (bid >> 3);   // 2016 = 8*252, bijective
  const int n   = swz / 63;
  const int oh0 = (swz - n * 63) * 2;             // <=124 (no tail: 126 = 63*2)

  const int lane = t & 63, w = t >> 6;
  const int wr = w >> 1;             // output row of this wave
  const int wh = w & 1;              // px 64-half within row
  const int lg = lane >> 4, ln = lane & 15;

  // staging roles: row rs, column cs (one c each, 4 ci-octets)
  const int rs = t >> 7;
  const int cs = t & 127;

  // B fragment byte-offsets within a buffer (chunk swizzle ni-invariant under +16c)
  int Bb[3];
  #pragma unroll
  for (int kw = 0; kw < 3; ++kw) {
    int c0 = wh * 64 + ln + kw;                   // +ni*16 <= 129 (pad cols zeroed)
    int ch = lg ^ ((c0 >> 1) & 3);
    Bb[kw] = wr * 8448 + c0 * 64 + ch * 16;       // + buf*16896 + ni*1024
  }
  const unsigned short* wlane = wt4 + lane * 8;   // + (p*8+mi)*512

  f32x4 acc[8][4];
  #pragma unroll
  for (int i = 0; i < 8; ++i)
    #pragma unroll
    for (int j = 0; j < 4; ++j)
      acc[i][j] = (f32x4){0.f, 0.f, 0.f, 0.f};

  float sv[4][8];                    // one group's x slice (32 VGPR)

  auto loadX = [&](int G) {          // 32 coalesced fp32 loads (issued, not waited)
    const int h = oh0 + rs + (G >> 1);            // <=127
    #pragma unroll
    for (int o = 0; o < 4; ++o) {
      const size_t base =
          ((size_t)((n * 64 + (G & 1) * 32 + o * 8) * 128 + h)) * 128 + cs;
      #pragma unroll
      for (int j = 0; j < 8; ++j)
        sv[o][j] = x[base + (size_t)j * 16384];   // 64 lanes x 4B contiguous
    }
  };
  auto writeX = [&](int buf) {       // 4 conflict-free ds_write_b128 (R6 pattern)
    char* dst = (char*)&sX[0][0][0][0] + buf * 16896 + rs * 8448 + cs * 64;
    #pragma unroll
    for (int o = 0; o < 4; ++o) {
      const int ch = o ^ ((cs >> 1) & 3);         // baked T2 swizzle (matches reads)
      uint4 v = make_uint4(packbf2(sv[o][0], sv[o][1]), packbf2(sv[o][2], sv[o][3]),
                           packbf2(sv[o][4], sv[o][5]), packbf2(sv[o][6], sv[o][7]));
      *(uint4*)(dst + ch * 16) = v;
    }
  };

  // prologue: zero pad cols 128..131 of both buffers/rows; stage group 0
  {
    int buf = t >> 7, r = (t >> 6) & 1, i = t & 63;
    *((unsigned*)((char*)&sX[0][0][0][0] + buf * 16896 + r * 8448 + 128 * 64) + i) = 0u;
  }
  loadX(0);
  writeX(0);
  asm volatile("s_waitcnt lgkmcnt(0)" ::: "memory");
  __builtin_amdgcn_s_barrier();
  __builtin_amdgcn_sched_barrier(0);

  #pragma unroll
  for (int p = 0; p < 18; ++p) {
    const int G = p / 3, kw = p - G * 3, buf = G & 1;

    if (kw == 0 && G < 5) {
      loadX(G + 1);                  // issue-early; consumed at kw=2 (~2.7 phases cover)
      __builtin_amdgcn_sched_barrier(0);
    }

    bf16x8 bfr[4];
    #pragma unroll
    for (int ni = 0; ni < 4; ++ni)
      bfr[ni] = *(const bf16x8*)((const char*)&sX[0][0][0][0] +
                                 buf * 16896 + Bb[kw] + ni * 1024);
    __builtin_amdgcn_s_setprio(1);
    #pragma unroll
    for (int mi = 0; mi < 8; ++mi) {              // af streamed (L1-shared, all waves same)
      bf16x8 af = *(const bf16x8*)(wlane + (p * 8 + mi) * 512);
      #pragma unroll
      for (int ni = 0; ni < 4; ++ni)
        acc[mi][ni] = __builtin_amdgcn_mfma_f32_16x16x32_bf16(
            af, bfr[ni], acc[mi][ni], 0, 0, 0);
    }
    __builtin_amdgcn_s_setprio(0);

    if (kw == 2 && G < 5) {
      writeX(buf ^ 1);               // write-late into next buffer (cvt waits on vmcnt)
      asm volatile("s_waitcnt lgkmcnt(0)" ::: "memory");
      __builtin_amdgcn_s_barrier();  // next buf staged; cur buf reads complete
      __builtin_amdgcn_sched_barrier(0);
    }
  }

  // epilogue: (acc + bias)*0.5, min over all 128 co; no LDS needed
  // C/D: col = ln (px within ni-frag), row = lg*4 + r -> co = mi*16 + lg*4 + r
  #pragma unroll
  for (int ni = 0; ni < 4; ++ni) {
    float m = 3.4e38f;
    #pragma unroll
    for (int mi = 0; mi < 8; ++mi)
      #pragma unroll
      for (int r = 0; r < 4; ++r)
        m = fminf(m, (acc[mi][ni][r] + bias[mi * 16 + lg * 4 + r]) * 0.5f);
    m = fminf(m, __shfl_xor(m, 16));
    m = fminf(m, __shfl_xor(m, 32));
    int col = wh * 64 + ni * 16 + ln;
    if (lg == 0 && col < OWw)
      out[((size_t)n * OHh + oh0 + wr) * OWw + col] = m;
  }
}

// ================= fallback (direct-compute path, used only if ws unusable) =========
__global__ __launch_bounds__(256, 2)
void conv_min_fb(const float* __restrict__ x, const float* __restrict__ w,
                 const float* __restrict__ bias, float* __restrict__ out) {
  __shared__ __align__(16) unsigned short sW[128][40];
  __shared__ __align__(16) unsigned short sX[128][40];
  __shared__ float sBias[COUT];
  __shared__ float sRed[2][128];
  const int t = threadIdx.x, bid = blockIdx.x;
  const int n = bid / OHh, oh = bid - n * OHh;
  if (t < COUT) sBias[t] = bias[t];
  const int hq = t & 7, q = t >> 3, c0 = q * 4;
  const int wco = t >> 1, whalf = t & 1;
  const int lane = t & 63, lg = lane >> 4, ln = lane & 15;
  const int wv = t >> 6, wc = wv & 1, wp = wv >> 1;
  f32x4 acc[4][4];
  #pragma unroll
  for (int i = 0; i < 4; ++i)
    #pragma unroll
    for (int j = 0; j < 4; ++j) acc[i][j] = (f32x4){0.f, 0.f, 0.f, 0.f};
  const float* xn = x + (size_t)n * CIN * CH * CW;
  for (int s = 0; s < 18; ++s) {
    const int kw_s = s / 6;
    const int rembase = (s - kw_s * 6) * 32;
    float4 xa[2], xb[2]; int kkp[2];
    #pragma unroll
    for (int pi = 0; pi < 2; ++pi) {
      const int kk = 2 * hq + 16 * pi; kkp[pi] = kk;
      int rem0 = rembase + kk, ci0 = rem0 / 3, kh0 = rem0 - ci0 * 3;
      int rem1 = rem0 + 1, ci1 = rem1 / 3, kh1 = rem1 - ci1 * 3;
      xa[pi] = *(const float4*)(xn + (ci0 * CH + (oh + kh0)) * CW + c0);
      xb[pi] = *(const float4*)(xn + (ci1 * CH + (oh + kh1)) * CW + c0);
    }
    unsigned tmp[8];
    #pragma unroll
    for (int e = 0; e < 8; ++e) {
      int kk = whalf * 16 + 2 * e;
      int rem0 = rembase + kk, ci0 = rem0 / 3, kh0 = rem0 - ci0 * 3;
      int rem1 = rem0 + 1, ci1 = rem1 / 3, kh1 = rem1 - ci1 * 3;
      tmp[e] = (unsigned)f2bf(w[wco * 576 + ci0 * 9 + kh0 * 3 + kw_s]) |
               ((unsigned)f2bf(w[wco * 576 + ci1 * 9 + kh1 * 3 + kw_s]) << 16);
    }
    __syncthreads();
    #pragma unroll
    for (int pi = 0; pi < 2; ++pi)
      #pragma unroll
      for (int j = 0; j < 4; ++j) {
        int p = c0 + j - kw_s;
        unsigned pk = (unsigned)f2bf(((const float*)&xa[pi])[j]) |
                      ((unsigned)f2bf(((const float*)&xb[pi])[j]) << 16);
        if (p >= 0) *(unsigned*)&sX[p][kkp[pi]] = pk;
      }
    *(uint4*)&sW[wco][whalf * 16] = make_uint4(tmp[0], tmp[1], tmp[2], tmp[3]);
    *(uint4*)&sW[wco][whalf * 16 + 8] = make_uint4(tmp[4], tmp[5], tmp[6], tmp[7]);
    __syncthreads();
    bf16x8 af[4], bfr[4];
    #pragma unroll
    for (int mi = 0; mi < 4; ++mi) af[mi] = *(const bf16x8*)&sW[wc * 64 + mi * 16 + ln][lg * 8];
    #pragma unroll
    for (int ni = 0; ni < 4; ++ni) bfr[ni] = *(const bf16x8*)&sX[wp * 64 + ni * 16 + ln][lg * 8];
    #pragma unroll
    for (int mi = 0; mi < 4; ++mi)
      #pragma unroll
      for (int ni = 0; ni < 4; ++ni)
        acc[mi][ni] = __builtin_amdgcn_mfma_f32_16x16x32_bf16(af[mi], bfr[ni], acc[mi][ni], 0, 0, 0);
  }
  #pragma unroll
  for (int ni = 0; ni < 4; ++ni) {
    float m = 3.4e38f;
    #pragma unroll
    for (int mi = 0; mi < 4; ++mi)
      #pragma unroll
      for (int r = 0; r < 4; ++r)
        m = fminf(m, (acc[mi][ni][r] + sBias[wc * 64 + mi * 16 + lg * 4 + r]) * 0.5f);
    m = fminf(m, __shfl_xor(m, 16));
    m = fminf(m, __shfl_xor(m, 32));
    if (lg == 0) sRed[wc][wp * 64 + ni * 16 + ln] = m;
  }
  __syncthreads();
  if (t < OWw) out[(size_t)(n * OHh + oh) * OWw + t] = fminf(sRed[0][t], sRed[1][t]);
}

extern "C" void kernel_launch(void* const* d_in, const int* in_sizes, int n_in,
                              void* d_out, int out_size, void* d_ws, size_t ws_size,
                              hipStream_t stream) {
  const float* x    = (const float*)d_in[0];
  const float* w    = (const float*)d_in[1];
  const float* bias = (const float*)d_in[2];
  float* out = (float*)d_out;

  const size_t WT_BYTES = (size_t)COUT * KTOT * 2;   // 147,456

  if (d_ws && ws_size >= WT_BYTES) {
    unsigned short* wt4 = (unsigned short*)d_ws;
    prep_wt4_kernel<<<(COUT * KTOT + 255) / 256, 256, 0, stream>>>(w, wt4);
    conv_min_mfma13<<<2016, 256, 0, stream>>>(x, wt4, bias, out);
  } else {
    conv_min_fb<<<CN * OHh, 256, 0, stream>>>(x, w, bias, out);
  }
}